// Round 11
// baseline (186.229 us; speedup 1.0000x reference)
//
#include <hip/hip_runtime.h>
#include <hip/hip_bf16.h>
#include <cstdint>

typedef short short8 __attribute__((ext_vector_type(8)));
typedef float f32x4 __attribute__((ext_vector_type(4)));

#define MFMA16(a, b, c) __builtin_amdgcn_mfma_f32_16x16x32_bf16((a), (b), (c), 0, 0, 0)

__device__ __forceinline__ unsigned short f2b(float f) {
    __hip_bfloat16 h = __float2bfloat16(f);
    return __builtin_bit_cast(unsigned short, h);
}

__device__ __forceinline__ void gl_lds16(const void* g, void* l) {
    __builtin_amdgcn_global_load_lds((const __attribute__((address_space(1))) void*)g,
                                     (__attribute__((address_space(3))) void*)l, 16, 0, 0);
}

// (1/8) * log2(e): QK^T scores land in log2 domain -> bare v_exp_f32 softmax
#define QSC 0.18033688011112042f

// ---------------- RMSNorm: fp32 x -> bf16 xn ----------------
__global__ void rmsnorm_kernel(const float* __restrict__ x, const float* __restrict__ scale,
                               unsigned short* __restrict__ xn) {
    const int row = blockIdx.x;
    const int tid = threadIdx.x;
    const float4* xr = (const float4*)(x + (size_t)row * 1024);
    float4 vx = xr[tid];
    float ss = vx.x * vx.x + vx.y * vx.y + vx.z * vx.z + vx.w * vx.w;
#pragma unroll
    for (int m = 1; m < 64; m <<= 1) ss += __shfl_xor(ss, m);
    __shared__ float wsum[4];
    if ((tid & 63) == 0) wsum[tid >> 6] = ss;
    __syncthreads();
    float tot = wsum[0] + wsum[1] + wsum[2] + wsum[3];
    float rs = rsqrtf(tot * (1.0f / 1024.0f) + 1e-6f);
    const float4* sr = (const float4*)scale;
    float4 sv = sr[tid];
    ushort4 r;
    r.x = f2b(vx.x * sv.x * rs);
    r.y = f2b(vx.y * sv.y * rs);
    r.z = f2b(vx.z * sv.z * rs);
    r.w = f2b(vx.w * sv.w * rs);
    *(ushort4*)(xn + (size_t)row * 1024 + tid * 4) = r;
}

// ---------------- f32 -> bf16 convert ----------------
__global__ void f2b_kernel(const float* __restrict__ in, unsigned short* __restrict__ outp, int n4) {
    int i = blockIdx.x * 256 + threadIdx.x;
    if (i < n4) {
        float4 vv = ((const float4*)in)[i];
        ushort4 r;
        r.x = f2b(vv.x);
        r.y = f2b(vv.y);
        r.z = f2b(vv.z);
        r.w = f2b(vv.w);
        ((ushort4*)outp)[i] = r;
    }
}

// ---------------- GEMM C = A * B^T (A: MxK bf16 row-major, B: NxK bf16 row-major) ----
// m97 structure: single-buffered 32 KB LDS, XOR chunk-swizzle (conflict-free ds_read_b128),
// global_load_lds width-16 staging, 2 barriers per K-step, high occupancy.
// EPI 0: scatter qkv; RoPE fused for q,k (q scaled by QSC); v TRANSPOSED (B,H,D,S)
// EPI 1: out[m][n] = acc + skip[m][n]  (fp32)
constexpr int BM = 128, BN = 128, BK = 64, KDIM = 1024, NT = KDIM / BK;

template <int EPI>
__launch_bounds__(256, 4) __global__
    void gemm_bt(const unsigned short* __restrict__ A, const unsigned short* __restrict__ Bw,
                 unsigned short* __restrict__ qo, unsigned short* __restrict__ ko,
                 unsigned short* __restrict__ vo, const float* __restrict__ skip,
                 float* __restrict__ out, const float* __restrict__ theta) {
    __shared__ unsigned short As[BM * BK];
    __shared__ unsigned short Bs[BN * BK];
    const int tid = threadIdx.x;
    const int lane = tid & 63, w = tid >> 6;
    const int wr = w >> 1, wc = w & 1;
    const int lr = lane & 15, lg = lane >> 4;
    // XCD-aware bijective swizzle: each XCD gets 8 consecutive by-rows.
    constexpr int NBX = (EPI == 0) ? 24 : 8;
    const int f = blockIdx.x;
    const int xcd = f & 7, wloc = f >> 3;
    const int g = xcd * (NBX * 8) + wloc;
    const int bx = g % NBX, by = g / NBX;
    const int m0 = by * BM;
    const int n0 = bx * BN;
    const int NCOL = (EPI == 0) ? 3072 : 1024;

    f32x4 acc[4][4] = {};

    // LDS[row][slot] = global[row][chunk slot ^ (row&7)]  (16B chunks, 8 per row)
    auto stage = [&](int kt) {
        const int k0 = kt * BK;
#pragma unroll
        for (int i = 0; i < 4; ++i) {
            int seg = i * 256 + tid;
            int row = seg >> 3, c8 = (seg & 7) ^ (row & 7);
            gl_lds16(A + (size_t)(m0 + row) * KDIM + k0 + c8 * 8, &As[(i * 256 + w * 64) * 8]);
            gl_lds16(Bw + (size_t)(n0 + row) * KDIM + k0 + c8 * 8, &Bs[(i * 256 + w * 64) * 8]);
        }
    };

    for (int kt = 0; kt < NT; ++kt) {
        stage(kt);
        __syncthreads();
#pragma unroll
        for (int kkc = 0; kkc < 2; ++kkc) {
            short8 a[4], b[4];
            const int slot = ((kkc * 4 + lg) ^ (lr & 7)) * 8;
#pragma unroll
            for (int m = 0; m < 4; ++m)
                a[m] = *(const short8*)&As[(wr * 64 + m * 16 + lr) * BK + slot];
#pragma unroll
            for (int n = 0; n < 4; ++n)
                b[n] = *(const short8*)&Bs[(wc * 64 + n * 16 + lr) * BK + slot];
#pragma unroll
            for (int m = 0; m < 4; ++m)
#pragma unroll
                for (int n = 0; n < 4; ++n) acc[m][n] = MFMA16(a[m], b[n], acc[m][n]);
        }
        __syncthreads();
    }

    if (EPI == 0) {
        // whole (block, wc) group is one output tensor c and one head h
        const int colb = n0 + wc * 64;
        const int c = colb >> 10, h = (colb >> 6) & 15;
#pragma unroll
        for (int m = 0; m < 4; ++m) {
            int grow0 = m0 + wr * 64 + m * 16 + lg * 4;
            int b = grow0 >> 10, s0 = grow0 & 1023;
            if (c == 2) {
#pragma unroll
                for (int n = 0; n < 4; ++n) {
                    int d = n * 16 + lr;
                    ushort4 r;
                    r.x = f2b(acc[m][n][0]);
                    r.y = f2b(acc[m][n][1]);
                    r.z = f2b(acc[m][n][2]);
                    r.w = f2b(acc[m][n][3]);
                    *(ushort4*)&vo[(((size_t)(b * 16 + h)) * 64 + d) * 1024 + s0] = r;
                }
            } else {
                unsigned short* dst = (c == 0) ? qo : ko;
                float sc = (c == 0) ? QSC : 1.0f;
#pragma unroll
                for (int j = 0; j < 4; ++j) {
                    int s = s0 + j;
                    float th = theta[((s * 16 + h) << 4) + lr];
                    float sn, cs;
                    __sincosf(th, &sn, &cs);
                    float x1 = acc[m][0][j], x2 = acc[m][1][j];
                    size_t rowb = (((size_t)(b * 16 + h)) * 1024 + s) * 64;
                    dst[rowb + lr]      = f2b((x1 * cs - x2 * sn) * sc);
                    dst[rowb + 16 + lr] = f2b((x2 * cs + x1 * sn) * sc);
                    dst[rowb + 32 + lr] = f2b(acc[m][2][j] * sc);
                    dst[rowb + 48 + lr] = f2b(acc[m][3][j] * sc);
                }
            }
        }
    } else {
#pragma unroll
        for (int m = 0; m < 4; ++m)
#pragma unroll
            for (int n = 0; n < 4; ++n) {
                int gcol = n0 + wc * 64 + n * 16 + lr;
#pragma unroll
                for (int j = 0; j < 4; ++j) {
                    int grow = m0 + wr * 64 + m * 16 + lg * 4 + j;
                    size_t idx = (size_t)grow * NCOL + gcol;
                    out[idx] = acc[m][n][j] + skip[idx];
                }
            }
    }
}

// ---------------- Flash attention (causal), barrier-free, global-direct ----------------
// q,k: (B,H,S,D) bf16 (q pre-scaled by QSC, rope applied).  vT: (B,H,D,S) bf16.
// o: (B,S,H*D) bf16. Each WAVE owns 32 q-rows and runs exactly its causal tile
// count; K and V^T fragments are read directly from global (L2-resident per-XCD
// working set, 64B-line-exact strided reads) -> zero __syncthreads, zero LDS
// staging, full TLP overlap. Swapped QK^T; in-register softmax; P routed via
// wave-private XOR-swizzled LDS scratch; coalesced O epilogue via LDS transpose.
// 2 independent waves per block; LPT (heavy row-groups first); bh->XCD binding.
__launch_bounds__(128, 4) __global__
    void attn_kernel(const unsigned short* __restrict__ q, const unsigned short* __restrict__ k,
                     const unsigned short* __restrict__ vt, unsigned short* __restrict__ o) {
    constexpr int S = 1024, D = 64;
    __shared__ unsigned Pls[2][16 * 32];      // per-wave P dwords, XOR-swizzled
    __shared__ unsigned short Ts[2][32 * 72]; // per-wave epilogue transpose
    const int tid = threadIdx.x, lane = tid & 63, wv = tid >> 6;
    const int lr = lane & 15, lg = lane >> 4;
    const int f = blockIdx.x;  // 0..2047
    const int bh = (f & 7) * 16 + ((f >> 3) & 15);
    const int pairi = f >> 7;                 // 0..15, LPT: heavy first
    const int g = 31 - (pairi * 2 + wv);      // row-group 0..31 (32 rows each)
    const int wrow0 = g * 32;
    const size_t base = (size_t)bh * (S * D);
    const int nkt = (g >> 1) + 1;

    short8 qf[2][2];
#pragma unroll
    for (int m = 0; m < 2; ++m) {
        const unsigned short* qp = q + base + (size_t)(wrow0 + m * 16 + lr) * D;
        qf[m][0] = *(const short8*)(qp + lg * 8);
        qf[m][1] = *(const short8*)(qp + 32 + lg * 8);
    }

    f32x4 of[2][4] = {};  // O[q = wrow0 + m*16 + lg*4 + j][d = 16*n2 + lr]
    float mrun[2] = {-1e30f, -1e30f};
    float lrun[2] = {0.f, 0.f};  // per-lane partial (own t-subset); reduced at end

    unsigned* Pw = &Pls[wv][0];
    const int swz = (lr & 7) << 2;  // keeps 16B alignment; spreads write banks

    for (int kt = 0; kt < nkt; ++kt) {
        // Swapped QK^T: sf[m][n][j] = S^T[t = kt*64+16n+lg*4+j][q = wrow0+m*16+lr]
        // K A-frag straight from global: lane reads 16B of row t = kt*64+16n+lr.
        const unsigned short* kb = k + base + (size_t)kt * 64 * D + lg * 8;
        f32x4 sf[2][4] = {};
        __builtin_amdgcn_s_setprio(1);
#pragma unroll
        for (int n = 0; n < 4; ++n) {
            const unsigned short* kr = kb + (n * 16 + lr) * D;
            short8 kf0 = *(const short8*)(kr);
            short8 kf1 = *(const short8*)(kr + 32);
#pragma unroll
            for (int m = 0; m < 2; ++m) {
                sf[m][n] = MFMA16(kf0, qf[m][0], sf[m][n]);
                sf[m][n] = MFMA16(kf1, qf[m][1], sf[m][n]);
            }
        }
        __builtin_amdgcn_s_setprio(0);

        if (kt == nkt - 1) {  // only the last tile can overlap the diagonal
#pragma unroll
            for (int m = 0; m < 2; ++m)
#pragma unroll
                for (int n = 0; n < 4; ++n)
#pragma unroll
                    for (int j = 0; j < 4; ++j) {
                        int t = kt * 64 + 16 * n + lg * 4 + j;
                        int qr = wrow0 + m * 16 + lr;
                        if (t > qr) sf[m][n][j] = -1e30f;
                    }
        }

#pragma unroll
        for (int m = 0; m < 2; ++m) {
            // in-lane max over 16 t-values, then 2 shfls across the 4 lanes sharing q
            float mx = -1e30f;
#pragma unroll
            for (int n = 0; n < 4; ++n)
                mx = fmaxf(mx, fmaxf(fmaxf(sf[m][n][0], sf[m][n][1]),
                                     fmaxf(sf[m][n][2], sf[m][n][3])));
            mx = fmaxf(mx, __shfl_xor(mx, 16));
            mx = fmaxf(mx, __shfl_xor(mx, 32));

            if (__any(mx > mrun[m] + 8.0f)) {
                float newm = fmaxf(mrun[m], mx);
                float sc = __builtin_amdgcn_exp2f(mrun[m] - newm);
                mrun[m] = newm;
                float psum = 0.f;
#pragma unroll
                for (int n = 0; n < 4; ++n)
#pragma unroll
                    for (int j = 0; j < 4; ++j) {
                        float p = __builtin_amdgcn_exp2f(sf[m][n][j] - newm);
                        sf[m][n][j] = p;
                        psum += p;
                    }
                lrun[m] = lrun[m] * sc + psum;
#pragma unroll
                for (int n2 = 0; n2 < 4; ++n2) of[m][n2] *= sc;
            } else {
                float mo = mrun[m];
                float psum = 0.f;
#pragma unroll
                for (int n = 0; n < 4; ++n)
#pragma unroll
                    for (int j = 0; j < 4; ++j) {
                        float p = __builtin_amdgcn_exp2f(sf[m][n][j] - mo);
                        sf[m][n][j] = p;
                        psum += p;
                    }
                lrun[m] += psum;
            }
        }

        // P -> PV A-frags through wave-private LDS dwords (no barrier: same wave).
        // Write: dword tp = 8n+2lg+w2 holds t = {2tp, 2tp+1} for q-row lr.
        // Read:  A-frag k-layout t = kkc*32 + 8lg + j  -> dwords tp = kkc*16+4lg+{0..3}.
        short8 pa[2][2];  // [m][kkc]
#pragma unroll
        for (int m = 0; m < 2; ++m) {
            unsigned Dk[4][2];
#pragma unroll
            for (int n = 0; n < 4; ++n)
#pragma unroll
                for (int w2 = 0; w2 < 2; ++w2)
                    Dk[n][w2] = (unsigned)f2b(sf[m][n][2 * w2]) |
                                ((unsigned)f2b(sf[m][n][2 * w2 + 1]) << 16);
#pragma unroll
            for (int n = 0; n < 4; ++n)
#pragma unroll
                for (int w2 = 0; w2 < 2; ++w2)
                    Pw[lr * 32 + ((8 * n + 2 * lg + w2) ^ swz)] = Dk[n][w2];
#pragma unroll
            for (int kkc = 0; kkc < 2; ++kkc)
                pa[m][kkc] = *(const short8*)&Pw[lr * 32 + ((kkc * 16 + 4 * lg) ^ swz)];
        }

        // PV: O[q][d] += P[q][t] * V[t][d]; V^T B-frag straight from global:
        // lane reads 16B of V^T row d = 16*n2+lr at cols kt*64 + kkc*32 + lg*8.
        const unsigned short* vb = vt + base + kt * 64 + lg * 8;
        __builtin_amdgcn_s_setprio(1);
#pragma unroll
        for (int n2 = 0; n2 < 4; ++n2) {
            const unsigned short* vr = vb + (size_t)(n2 * 16 + lr) * S;
            short8 bv0 = *(const short8*)(vr);
            short8 bv1 = *(const short8*)(vr + 32);
#pragma unroll
            for (int m = 0; m < 2; ++m) {
                of[m][n2] = MFMA16(pa[m][0], bv0, of[m][n2]);
                of[m][n2] = MFMA16(pa[m][1], bv1, of[m][n2]);
            }
        }
        __builtin_amdgcn_s_setprio(0);
    }

    // final l per q-row, redistributed through the wave-private scratch
    float* Lw = (float*)&Pls[wv][0];
#pragma unroll
    for (int m = 0; m < 2; ++m) {
        float l = lrun[m];
        l += __shfl_xor(l, 16);
        l += __shfl_xor(l, 32);
        Lw[m * 16 + lr] = l;  // all lg write the same value
    }

    // O epilogue: normalize, transpose through wave-private LDS (row stride 72
    // ushorts = 144B, 16B-aligned), then coalesced 16B stores.
    unsigned short* Tw = &Ts[wv][0];  // 32 rows x 72
    const int bb = bh >> 4, h = bh & 15;
#pragma unroll
    for (int m = 0; m < 2; ++m)
#pragma unroll
        for (int j = 0; j < 4; ++j) {
            float inv = 1.f / Lw[m * 16 + lg * 4 + j];
            int row = m * 16 + lg * 4 + j;
#pragma unroll
            for (int n2 = 0; n2 < 4; ++n2)
                Tw[row * 72 + n2 * 16 + lr] = f2b(of[m][n2][j] * inv);
        }
#pragma unroll
    for (int i = 0; i < 4; ++i) {
        int row = i * 8 + lg * 2 + (lr >> 3);
        short8 v = *(const short8*)&Tw[row * 72 + (lr & 7) * 8];
        size_t ob = ((size_t)(bb * 1024 + wrow0 + row)) * 1024 + h * 64 + (lr & 7) * 8;
        *(short8*)&o[ob] = v;
    }
}

extern "C" void kernel_launch(void* const* d_in, const int* in_sizes, int n_in, void* d_out,
                              int out_size, void* d_ws, size_t ws_size, hipStream_t stream) {
    const float* x = (const float*)d_in[0];
    const float* scale = (const float*)d_in[1];
    const float* w_qkv = (const float*)d_in[2];
    const float* w_out = (const float*)d_in[3];
    const float* theta = (const float*)d_in[4];
    float* out = (float*)d_out;

    char* p = (char*)d_ws;
    unsigned short* xn = (unsigned short*)p;      p += (size_t)8192 * 1024 * 2;
    unsigned short* wqb = (unsigned short*)p;     p += (size_t)3072 * 1024 * 2;
    unsigned short* wob = (unsigned short*)p;     p += (size_t)1024 * 1024 * 2;
    unsigned short* qb_ = (unsigned short*)p;     p += (size_t)128 * 1024 * 64 * 2;
    unsigned short* kb_ = (unsigned short*)p;     p += (size_t)128 * 1024 * 64 * 2;
    unsigned short* vb_ = (unsigned short*)p;     p += (size_t)128 * 1024 * 64 * 2;  // V^T (B,H,D,S)
    unsigned short* ob_ = (unsigned short*)p;     p += (size_t)8192 * 1024 * 2;

    rmsnorm_kernel<<<8192, 256, 0, stream>>>(x, scale, xn);
    f2b_kernel<<<3072, 256, 0, stream>>>(w_qkv, wqb, 786432);
    f2b_kernel<<<1024, 256, 0, stream>>>(w_out, wob, 262144);
    gemm_bt<0><<<1536, 256, 0, stream>>>(xn, wqb, qb_, kb_, vb_, nullptr, nullptr, theta);
    attn_kernel<<<2048, 128, 0, stream>>>(qb_, kb_, vb_, ob_);
    gemm_bt<1><<<512, 256, 0, stream>>>(ob_, wob, nullptr, nullptr, nullptr, x, out, nullptr);
}

// Round 12
// 169.761 us; speedup vs baseline: 1.0970x; 1.0970x over previous
//
#include <hip/hip_runtime.h>
#include <hip/hip_bf16.h>
#include <cstdint>

typedef short short8 __attribute__((ext_vector_type(8)));
typedef float f32x4 __attribute__((ext_vector_type(4)));

#define MFMA16(a, b, c) __builtin_amdgcn_mfma_f32_16x16x32_bf16((a), (b), (c), 0, 0, 0)

__device__ __forceinline__ unsigned short f2b(float f) {
    __hip_bfloat16 h = __float2bfloat16(f);
    return __builtin_bit_cast(unsigned short, h);
}

__device__ __forceinline__ void gl_lds16(const void* g, void* l) {
    __builtin_amdgcn_global_load_lds((const __attribute__((address_space(1))) void*)g,
                                     (__attribute__((address_space(3))) void*)l, 16, 0, 0);
}

// (1/8) * log2(e): QK^T scores land in log2 domain -> bare v_exp_f32 softmax
#define QSC 0.18033688011112042f

// ---------------- RMSNorm: fp32 x -> bf16 xn ----------------
__global__ void rmsnorm_kernel(const float* __restrict__ x, const float* __restrict__ scale,
                               unsigned short* __restrict__ xn) {
    const int row = blockIdx.x;
    const int tid = threadIdx.x;
    const float4* xr = (const float4*)(x + (size_t)row * 1024);
    float4 vx = xr[tid];
    float ss = vx.x * vx.x + vx.y * vx.y + vx.z * vx.z + vx.w * vx.w;
#pragma unroll
    for (int m = 1; m < 64; m <<= 1) ss += __shfl_xor(ss, m);
    __shared__ float wsum[4];
    if ((tid & 63) == 0) wsum[tid >> 6] = ss;
    __syncthreads();
    float tot = wsum[0] + wsum[1] + wsum[2] + wsum[3];
    float rs = rsqrtf(tot * (1.0f / 1024.0f) + 1e-6f);
    const float4* sr = (const float4*)scale;
    float4 sv = sr[tid];
    ushort4 r;
    r.x = f2b(vx.x * sv.x * rs);
    r.y = f2b(vx.y * sv.y * rs);
    r.z = f2b(vx.z * sv.z * rs);
    r.w = f2b(vx.w * sv.w * rs);
    *(ushort4*)(xn + (size_t)row * 1024 + tid * 4) = r;
}

// ---------------- f32 -> bf16 convert ----------------
__global__ void f2b_kernel(const float* __restrict__ in, unsigned short* __restrict__ outp, int n4) {
    int i = blockIdx.x * 256 + threadIdx.x;
    if (i < n4) {
        float4 vv = ((const float4*)in)[i];
        ushort4 r;
        r.x = f2b(vv.x);
        r.y = f2b(vv.y);
        r.z = f2b(vv.z);
        r.w = f2b(vv.w);
        ((ushort4*)outp)[i] = r;
    }
}

// ---------------- GEMM C = A * B^T (A: MxK bf16 row-major, B: NxK bf16 row-major) ----
// m97 structure: single-buffered 32 KB LDS, XOR chunk-swizzle (conflict-free ds_read_b128),
// global_load_lds width-16 staging, 2 barriers per K-step, high occupancy.
// EPI 0: scatter qkv; RoPE fused for q,k (q scaled by QSC); v TRANSPOSED (B,H,D,S)
// EPI 1: out[m][n] = acc + skip[m][n]  (fp32)
constexpr int BM = 128, BN = 128, BK = 64, KDIM = 1024, NT = KDIM / BK;

template <int EPI>
__launch_bounds__(256, 4) __global__
    void gemm_bt(const unsigned short* __restrict__ A, const unsigned short* __restrict__ Bw,
                 unsigned short* __restrict__ qo, unsigned short* __restrict__ ko,
                 unsigned short* __restrict__ vo, const float* __restrict__ skip,
                 float* __restrict__ out, const float* __restrict__ theta) {
    __shared__ unsigned short As[BM * BK];
    __shared__ unsigned short Bs[BN * BK];
    const int tid = threadIdx.x;
    const int lane = tid & 63, w = tid >> 6;
    const int wr = w >> 1, wc = w & 1;
    const int lr = lane & 15, lg = lane >> 4;
    // XCD-aware bijective swizzle: each XCD gets 8 consecutive by-rows.
    constexpr int NBX = (EPI == 0) ? 24 : 8;
    const int f = blockIdx.x;
    const int xcd = f & 7, wloc = f >> 3;
    const int g = xcd * (NBX * 8) + wloc;
    const int bx = g % NBX, by = g / NBX;
    const int m0 = by * BM;
    const int n0 = bx * BN;
    const int NCOL = (EPI == 0) ? 3072 : 1024;

    f32x4 acc[4][4] = {};

    // LDS[row][slot] = global[row][chunk slot ^ (row&7)]  (16B chunks, 8 per row)
    auto stage = [&](int kt) {
        const int k0 = kt * BK;
#pragma unroll
        for (int i = 0; i < 4; ++i) {
            int seg = i * 256 + tid;
            int row = seg >> 3, c8 = (seg & 7) ^ (row & 7);
            gl_lds16(A + (size_t)(m0 + row) * KDIM + k0 + c8 * 8, &As[(i * 256 + w * 64) * 8]);
            gl_lds16(Bw + (size_t)(n0 + row) * KDIM + k0 + c8 * 8, &Bs[(i * 256 + w * 64) * 8]);
        }
    };

    for (int kt = 0; kt < NT; ++kt) {
        stage(kt);
        __syncthreads();
#pragma unroll
        for (int kkc = 0; kkc < 2; ++kkc) {
            short8 a[4], b[4];
            const int slot = ((kkc * 4 + lg) ^ (lr & 7)) * 8;
#pragma unroll
            for (int m = 0; m < 4; ++m)
                a[m] = *(const short8*)&As[(wr * 64 + m * 16 + lr) * BK + slot];
#pragma unroll
            for (int n = 0; n < 4; ++n)
                b[n] = *(const short8*)&Bs[(wc * 64 + n * 16 + lr) * BK + slot];
#pragma unroll
            for (int m = 0; m < 4; ++m)
#pragma unroll
                for (int n = 0; n < 4; ++n) acc[m][n] = MFMA16(a[m], b[n], acc[m][n]);
        }
        __syncthreads();
    }

    if (EPI == 0) {
        // whole (block, wc) group is one output tensor c and one head h
        const int colb = n0 + wc * 64;
        const int c = colb >> 10, h = (colb >> 6) & 15;
#pragma unroll
        for (int m = 0; m < 4; ++m) {
            int grow0 = m0 + wr * 64 + m * 16 + lg * 4;
            int b = grow0 >> 10, s0 = grow0 & 1023;
            if (c == 2) {
#pragma unroll
                for (int n = 0; n < 4; ++n) {
                    int d = n * 16 + lr;
                    ushort4 r;
                    r.x = f2b(acc[m][n][0]);
                    r.y = f2b(acc[m][n][1]);
                    r.z = f2b(acc[m][n][2]);
                    r.w = f2b(acc[m][n][3]);
                    *(ushort4*)&vo[(((size_t)(b * 16 + h)) * 64 + d) * 1024 + s0] = r;
                }
            } else {
                unsigned short* dst = (c == 0) ? qo : ko;
                float sc = (c == 0) ? QSC : 1.0f;
#pragma unroll
                for (int j = 0; j < 4; ++j) {
                    int s = s0 + j;
                    float th = theta[((s * 16 + h) << 4) + lr];
                    float sn, cs;
                    __sincosf(th, &sn, &cs);
                    float x1 = acc[m][0][j], x2 = acc[m][1][j];
                    size_t rowb = (((size_t)(b * 16 + h)) * 1024 + s) * 64;
                    dst[rowb + lr]      = f2b((x1 * cs - x2 * sn) * sc);
                    dst[rowb + 16 + lr] = f2b((x2 * cs + x1 * sn) * sc);
                    dst[rowb + 32 + lr] = f2b(acc[m][2][j] * sc);
                    dst[rowb + 48 + lr] = f2b(acc[m][3][j] * sc);
                }
            }
        }
    } else {
#pragma unroll
        for (int m = 0; m < 4; ++m)
#pragma unroll
            for (int n = 0; n < 4; ++n) {
                int gcol = n0 + wc * 64 + n * 16 + lr;
#pragma unroll
                for (int j = 0; j < 4; ++j) {
                    int grow = m0 + wr * 64 + m * 16 + lg * 4 + j;
                    size_t idx = (size_t)grow * NCOL + gcol;
                    out[idx] = acc[m][n][j] + skip[idx];
                }
            }
    }
}

// ---------------- Flash attention (causal), QBLK=128, swapped-operand ----------------
// q,k: (B,H,S,D) bf16 (q pre-scaled by QSC, rope applied).  vT: (B,H,D,S) bf16.
// o: (B,S,H*D) bf16. Swapped QK^T -> lane holds S^T[t][q=lr]; softmax in-register
// (2 shfls). P routed to PV A-fragment via a wave-private XOR-swizzled LDS dword
// scratch. O epilogue transposed through the dead K/V LDS -> coalesced 16B stores.
// LPT stripes (qb descending, round-8 ordering); bh->XCD binding via f&7.
__launch_bounds__(256, 4) __global__
    void attn_kernel(const unsigned short* __restrict__ q, const unsigned short* __restrict__ k,
                     const unsigned short* __restrict__ vt, unsigned short* __restrict__ o) {
    constexpr int S = 1024, D = 64;
    __shared__ unsigned short KVs[4][4096];  // [buf]=K0,K1, [2+buf]=V0,V1; chunk-swizzled
    __shared__ unsigned Pls[4][16 * 32];     // per-wave P dwords, XOR-swizzled
    const int tid = threadIdx.x, lane = tid & 63, w = tid >> 6;
    const int lr = lane & 15, lg = lane >> 4;
    // LPT stripes of 128 blocks, qb descending; bh->XCD binding via f&7.
    const int f = blockIdx.x;  // 0..1023
    const int qb = 7 - (f >> 7);
    const int bh = (f & 7) * 16 + ((f >> 3) & 15);
    const int qs = qb * 128;
    const size_t base = (size_t)bh * (S * D);
    const int wrow0 = qs + w * 32;

    short8 qf[2][2];
#pragma unroll
    for (int m = 0; m < 2; ++m) {
        const unsigned short* qp = q + base + (size_t)(wrow0 + m * 16 + lr) * D;
        qf[m][0] = *(const short8*)(qp + lg * 8);
        qf[m][1] = *(const short8*)(qp + 32 + lg * 8);
    }

    f32x4 of[2][4] = {};  // O[q = wrow0 + m*16 + lg*4 + j][d = 16*n2 + lr]
    float mrun[2] = {-1e30f, -1e30f};
    float lrun[2] = {0.f, 0.f};  // per-lane partial (own t-subset); reduced at end

    const int nkt = 2 * qb + 2;

    auto stageK = [&](int buf, int kt) {
#pragma unroll
        for (int i = 0; i < 2; ++i) {
            int seg = i * 256 + tid;
            int row = seg >> 3, c8 = (seg & 7) ^ (row & 7);
            gl_lds16(k + base + (size_t)(kt * 64 + row) * D + c8 * 8,
                     &KVs[buf][(i * 256 + w * 64) * 8]);
        }
    };
    auto stageV = [&](int buf, int kt) {
#pragma unroll
        for (int i = 0; i < 2; ++i) {
            int seg = i * 256 + tid;
            int row = seg >> 3, c8 = (seg & 7) ^ (row & 7);
            gl_lds16(vt + base + (size_t)row * S + kt * 64 + c8 * 8,
                     &KVs[2 + buf][(i * 256 + w * 64) * 8]);
        }
    };

    unsigned* Pw = &Pls[w][0];
    const int swz = (lr & 7) << 2;  // keeps 16B alignment; spreads write banks

    stageK(0, 0);
    stageV(0, 0);
    __syncthreads();

    for (int kt = 0; kt < nkt; ++kt) {
        const int b = kt & 1;
        if (kt + 1 < nkt) {
            stageK(b ^ 1, kt + 1);
            stageV(b ^ 1, kt + 1);
        }

        if (kt * 64 <= wrow0 + 31) {  // wave-uniform: this wave has unmasked rows
            // Swapped QK^T: sf[m][n][j] = S^T[t = kt*64+16n+lg*4+j][q = wrow0+m*16+lr]
            f32x4 sf[2][4] = {};
            __builtin_amdgcn_s_setprio(1);
#pragma unroll
            for (int n = 0; n < 4; ++n) {
                const int r = n * 16 + lr;
#pragma unroll
                for (int kkc = 0; kkc < 2; ++kkc) {
                    short8 kf =
                        *(const short8*)&KVs[b][r * 64 + (((kkc * 4 + lg) ^ (lr & 7)) * 8)];
#pragma unroll
                    for (int m = 0; m < 2; ++m) sf[m][n] = MFMA16(kf, qf[m][kkc], sf[m][n]);
                }
            }
            __builtin_amdgcn_s_setprio(0);

            if (kt * 64 + 63 > wrow0) {  // tile overlaps diagonal for this wave
#pragma unroll
                for (int m = 0; m < 2; ++m)
#pragma unroll
                    for (int n = 0; n < 4; ++n)
#pragma unroll
                        for (int j = 0; j < 4; ++j) {
                            int t = kt * 64 + 16 * n + lg * 4 + j;
                            int qr = wrow0 + m * 16 + lr;
                            if (t > qr) sf[m][n][j] = -1e30f;
                        }
            }

#pragma unroll
            for (int m = 0; m < 2; ++m) {
                // in-lane max over 16 t-values, then 2 shfls across the 4 lanes sharing q
                float mx = -1e30f;
#pragma unroll
                for (int n = 0; n < 4; ++n)
                    mx = fmaxf(mx, fmaxf(fmaxf(sf[m][n][0], sf[m][n][1]),
                                         fmaxf(sf[m][n][2], sf[m][n][3])));
                mx = fmaxf(mx, __shfl_xor(mx, 16));
                mx = fmaxf(mx, __shfl_xor(mx, 32));

                if (__any(mx > mrun[m] + 8.0f)) {
                    float newm = fmaxf(mrun[m], mx);
                    float sc = __builtin_amdgcn_exp2f(mrun[m] - newm);
                    mrun[m] = newm;
                    float psum = 0.f;
#pragma unroll
                    for (int n = 0; n < 4; ++n)
#pragma unroll
                        for (int j = 0; j < 4; ++j) {
                            float p = __builtin_amdgcn_exp2f(sf[m][n][j] - newm);
                            sf[m][n][j] = p;
                            psum += p;
                        }
                    lrun[m] = lrun[m] * sc + psum;
#pragma unroll
                    for (int n2 = 0; n2 < 4; ++n2) of[m][n2] *= sc;
                } else {
                    float mo = mrun[m];
                    float psum = 0.f;
#pragma unroll
                    for (int n = 0; n < 4; ++n)
#pragma unroll
                        for (int j = 0; j < 4; ++j) {
                            float p = __builtin_amdgcn_exp2f(sf[m][n][j] - mo);
                            sf[m][n][j] = p;
                            psum += p;
                        }
                    lrun[m] += psum;
                }
            }

            // P -> PV A-frags through wave-private LDS dwords.
            // Write: dword tp = 8n+2lg+w2 holds t = {2tp, 2tp+1} for q-row lr.
            // Read:  A-frag k-layout t = kkc*32 + 8lg + j  -> dwords tp = kkc*16+4lg+{0..3}.
            short8 pa[2][2];  // [m][kkc]
#pragma unroll
            for (int m = 0; m < 2; ++m) {
                unsigned Dk[4][2];
#pragma unroll
                for (int n = 0; n < 4; ++n)
#pragma unroll
                    for (int w2 = 0; w2 < 2; ++w2)
                        Dk[n][w2] = (unsigned)f2b(sf[m][n][2 * w2]) |
                                    ((unsigned)f2b(sf[m][n][2 * w2 + 1]) << 16);
#pragma unroll
                for (int n = 0; n < 4; ++n)
#pragma unroll
                    for (int w2 = 0; w2 < 2; ++w2)
                        Pw[lr * 32 + ((8 * n + 2 * lg + w2) ^ swz)] = Dk[n][w2];
#pragma unroll
                for (int kkc = 0; kkc < 2; ++kkc)
                    pa[m][kkc] = *(const short8*)&Pw[lr * 32 + ((kkc * 16 + 4 * lg) ^ swz)];
            }

            // PV: O[q][d] += P[q][t] * V[t][d]; V^T-frag read identical to K-frag
            __builtin_amdgcn_s_setprio(1);
#pragma unroll
            for (int kkc = 0; kkc < 2; ++kkc) {
#pragma unroll
                for (int n2 = 0; n2 < 4; ++n2) {
                    const int r = n2 * 16 + lr;
                    short8 bv =
                        *(const short8*)&KVs[2 + b][r * 64 + (((kkc * 4 + lg) ^ (lr & 7)) * 8)];
#pragma unroll
                    for (int m = 0; m < 2; ++m) of[m][n2] = MFMA16(pa[m][kkc], bv, of[m][n2]);
                }
            }
            __builtin_amdgcn_s_setprio(0);
        }

        __syncthreads();
    }

    // final l per q-row, redistributed through the wave-private scratch
    float* Lw = (float*)&Pls[w][0];
#pragma unroll
    for (int m = 0; m < 2; ++m) {
        float l = lrun[m];
        l += __shfl_xor(l, 16);
        l += __shfl_xor(l, 32);
        Lw[m * 16 + lr] = l;  // all lg write the same value
    }

    // O epilogue: normalize, transpose through dead K/V LDS (wave-private region,
    // row stride 72 ushorts = 144B, 16B-aligned), then coalesced 16B stores.
    unsigned short* Ts = &KVs[0][0] + w * 2304;  // 32 rows x 72
    const int bb = bh >> 4, h = bh & 15;
#pragma unroll
    for (int m = 0; m < 2; ++m)
#pragma unroll
        for (int j = 0; j < 4; ++j) {
            float inv = 1.f / Lw[m * 16 + lg * 4 + j];
            int row = m * 16 + lg * 4 + j;
#pragma unroll
            for (int n2 = 0; n2 < 4; ++n2)
                Ts[row * 72 + n2 * 16 + lr] = f2b(of[m][n2][j] * inv);
        }
#pragma unroll
    for (int i = 0; i < 4; ++i) {
        int row = i * 8 + lg * 2 + (lr >> 3);
        short8 v = *(const short8*)&Ts[row * 72 + (lr & 7) * 8];
        size_t ob = ((size_t)(bb * 1024 + wrow0 + row)) * 1024 + h * 64 + (lr & 7) * 8;
        *(short8*)&o[ob] = v;
    }
}

extern "C" void kernel_launch(void* const* d_in, const int* in_sizes, int n_in, void* d_out,
                              int out_size, void* d_ws, size_t ws_size, hipStream_t stream) {
    const float* x = (const float*)d_in[0];
    const float* scale = (const float*)d_in[1];
    const float* w_qkv = (const float*)d_in[2];
    const float* w_out = (const float*)d_in[3];
    const float* theta = (const float*)d_in[4];
    float* out = (float*)d_out;

    char* p = (char*)d_ws;
    unsigned short* xn = (unsigned short*)p;      p += (size_t)8192 * 1024 * 2;
    unsigned short* wqb = (unsigned short*)p;     p += (size_t)3072 * 1024 * 2;
    unsigned short* wob = (unsigned short*)p;     p += (size_t)1024 * 1024 * 2;
    unsigned short* qb_ = (unsigned short*)p;     p += (size_t)128 * 1024 * 64 * 2;
    unsigned short* kb_ = (unsigned short*)p;     p += (size_t)128 * 1024 * 64 * 2;
    unsigned short* vb_ = (unsigned short*)p;     p += (size_t)128 * 1024 * 64 * 2;  // V^T (B,H,D,S)
    unsigned short* ob_ = (unsigned short*)p;     p += (size_t)8192 * 1024 * 2;

    rmsnorm_kernel<<<8192, 256, 0, stream>>>(x, scale, xn);
    f2b_kernel<<<3072, 256, 0, stream>>>(w_qkv, wqb, 786432);
    f2b_kernel<<<1024, 256, 0, stream>>>(w_out, wob, 262144);
    gemm_bt<0><<<1536, 256, 0, stream>>>(xn, wqb, qb_, kb_, vb_, nullptr, nullptr, theta);
    attn_kernel<<<1024, 256, 0, stream>>>(qb_, kb_, vb_, ob_);
    gemm_bt<1><<<512, 256, 0, stream>>>(ob_, wob, nullptr, nullptr, nullptr, x, out, nullptr);
}

// Round 13
// 159.573 us; speedup vs baseline: 1.1670x; 1.0638x over previous
//
#include <hip/hip_runtime.h>
#include <hip/hip_bf16.h>
#include <cstdint>

typedef short short8 __attribute__((ext_vector_type(8)));
typedef float f32x4 __attribute__((ext_vector_type(4)));

#define MFMA16(a, b, c) __builtin_amdgcn_mfma_f32_16x16x32_bf16((a), (b), (c), 0, 0, 0)

__device__ __forceinline__ unsigned short f2b(float f) {
    __hip_bfloat16 h = __float2bfloat16(f);
    return __builtin_bit_cast(unsigned short, h);
}

__device__ __forceinline__ void gl_lds16(const void* g, void* l) {
    __builtin_amdgcn_global_load_lds((const __attribute__((address_space(1))) void*)g,
                                     (__attribute__((address_space(3))) void*)l, 16, 0, 0);
}

// (1/8) * log2(e): QK^T scores land in log2 domain -> bare v_exp_f32 softmax
#define QSC 0.18033688011112042f

// ---------------- RMSNorm: fp32 x -> bf16 xn ----------------
__global__ void rmsnorm_kernel(const float* __restrict__ x, const float* __restrict__ scale,
                               unsigned short* __restrict__ xn) {
    const int row = blockIdx.x;
    const int tid = threadIdx.x;
    const float4* xr = (const float4*)(x + (size_t)row * 1024);
    float4 vx = xr[tid];
    float ss = vx.x * vx.x + vx.y * vx.y + vx.z * vx.z + vx.w * vx.w;
#pragma unroll
    for (int m = 1; m < 64; m <<= 1) ss += __shfl_xor(ss, m);
    __shared__ float wsum[4];
    if ((tid & 63) == 0) wsum[tid >> 6] = ss;
    __syncthreads();
    float tot = wsum[0] + wsum[1] + wsum[2] + wsum[3];
    float rs = rsqrtf(tot * (1.0f / 1024.0f) + 1e-6f);
    const float4* sr = (const float4*)scale;
    float4 sv = sr[tid];
    ushort4 r;
    r.x = f2b(vx.x * sv.x * rs);
    r.y = f2b(vx.y * sv.y * rs);
    r.z = f2b(vx.z * sv.z * rs);
    r.w = f2b(vx.w * sv.w * rs);
    *(ushort4*)(xn + (size_t)row * 1024 + tid * 4) = r;
}

// ---------------- f32 -> bf16 convert ----------------
__global__ void f2b_kernel(const float* __restrict__ in, unsigned short* __restrict__ outp, int n4) {
    int i = blockIdx.x * 256 + threadIdx.x;
    if (i < n4) {
        float4 vv = ((const float4*)in)[i];
        ushort4 r;
        r.x = f2b(vv.x);
        r.y = f2b(vv.y);
        r.z = f2b(vv.z);
        r.w = f2b(vv.w);
        ((ushort4*)outp)[i] = r;
    }
}

// ---------------- GEMM C = A * B^T (A: MxK bf16 row-major, B: NxK bf16 row-major) ----
// m97 structure: single-buffered 32 KB LDS, XOR chunk-swizzle (conflict-free ds_read_b128),
// global_load_lds width-16 staging, 2 barriers per K-step, high occupancy.
// EPI 0: scatter qkv; RoPE fused for q,k (q scaled by QSC); v TRANSPOSED (B,H,D,S)
// EPI 1: out[m][n] = acc + skip[m][n]  (fp32)
constexpr int BM = 128, BN = 128, BK = 64, KDIM = 1024, NT = KDIM / BK;

template <int EPI>
__launch_bounds__(256, 4) __global__
    void gemm_bt(const unsigned short* __restrict__ A, const unsigned short* __restrict__ Bw,
                 unsigned short* __restrict__ qo, unsigned short* __restrict__ ko,
                 unsigned short* __restrict__ vo, const float* __restrict__ skip,
                 float* __restrict__ out, const float* __restrict__ theta) {
    __shared__ unsigned short As[BM * BK];
    __shared__ unsigned short Bs[BN * BK];
    const int tid = threadIdx.x;
    const int lane = tid & 63, w = tid >> 6;
    const int wr = w >> 1, wc = w & 1;
    const int lr = lane & 15, lg = lane >> 4;
    // XCD-aware bijective swizzle: each XCD gets 8 consecutive by-rows.
    constexpr int NBX = (EPI == 0) ? 24 : 8;
    const int f = blockIdx.x;
    const int xcd = f & 7, wloc = f >> 3;
    const int g = xcd * (NBX * 8) + wloc;
    const int bx = g % NBX, by = g / NBX;
    const int m0 = by * BM;
    const int n0 = bx * BN;
    const int NCOL = (EPI == 0) ? 3072 : 1024;

    f32x4 acc[4][4] = {};

    // LDS[row][slot] = global[row][chunk slot ^ (row&7)]  (16B chunks, 8 per row)
    auto stage = [&](int kt) {
        const int k0 = kt * BK;
#pragma unroll
        for (int i = 0; i < 4; ++i) {
            int seg = i * 256 + tid;
            int row = seg >> 3, c8 = (seg & 7) ^ (row & 7);
            gl_lds16(A + (size_t)(m0 + row) * KDIM + k0 + c8 * 8, &As[(i * 256 + w * 64) * 8]);
            gl_lds16(Bw + (size_t)(n0 + row) * KDIM + k0 + c8 * 8, &Bs[(i * 256 + w * 64) * 8]);
        }
    };

    for (int kt = 0; kt < NT; ++kt) {
        stage(kt);
        __syncthreads();
#pragma unroll
        for (int kkc = 0; kkc < 2; ++kkc) {
            short8 a[4], b[4];
            const int slot = ((kkc * 4 + lg) ^ (lr & 7)) * 8;
#pragma unroll
            for (int m = 0; m < 4; ++m)
                a[m] = *(const short8*)&As[(wr * 64 + m * 16 + lr) * BK + slot];
#pragma unroll
            for (int n = 0; n < 4; ++n)
                b[n] = *(const short8*)&Bs[(wc * 64 + n * 16 + lr) * BK + slot];
#pragma unroll
            for (int m = 0; m < 4; ++m)
#pragma unroll
                for (int n = 0; n < 4; ++n) acc[m][n] = MFMA16(a[m], b[n], acc[m][n]);
        }
        __syncthreads();
    }

    if (EPI == 0) {
        // whole (block, wc) group is one output tensor c and one head h
        const int colb = n0 + wc * 64;
        const int c = colb >> 10, h = (colb >> 6) & 15;
#pragma unroll
        for (int m = 0; m < 4; ++m) {
            int grow0 = m0 + wr * 64 + m * 16 + lg * 4;
            int b = grow0 >> 10, s0 = grow0 & 1023;
            if (c == 2) {
#pragma unroll
                for (int n = 0; n < 4; ++n) {
                    int d = n * 16 + lr;
                    ushort4 r;
                    r.x = f2b(acc[m][n][0]);
                    r.y = f2b(acc[m][n][1]);
                    r.z = f2b(acc[m][n][2]);
                    r.w = f2b(acc[m][n][3]);
                    *(ushort4*)&vo[(((size_t)(b * 16 + h)) * 64 + d) * 1024 + s0] = r;
                }
            } else {
                unsigned short* dst = (c == 0) ? qo : ko;
                float sc = (c == 0) ? QSC : 1.0f;
#pragma unroll
                for (int j = 0; j < 4; ++j) {
                    int s = s0 + j;
                    float th = theta[((s * 16 + h) << 4) + lr];
                    float sn, cs;
                    __sincosf(th, &sn, &cs);
                    float x1 = acc[m][0][j], x2 = acc[m][1][j];
                    size_t rowb = (((size_t)(b * 16 + h)) * 1024 + s) * 64;
                    dst[rowb + lr]      = f2b((x1 * cs - x2 * sn) * sc);
                    dst[rowb + 16 + lr] = f2b((x2 * cs + x1 * sn) * sc);
                    dst[rowb + 32 + lr] = f2b(acc[m][2][j] * sc);
                    dst[rowb + 48 + lr] = f2b(acc[m][3][j] * sc);
                }
            }
        }
    } else {
#pragma unroll
        for (int m = 0; m < 4; ++m)
#pragma unroll
            for (int n = 0; n < 4; ++n) {
                int gcol = n0 + wc * 64 + n * 16 + lr;
#pragma unroll
                for (int j = 0; j < 4; ++j) {
                    int grow = m0 + wr * 64 + m * 16 + lg * 4 + j;
                    size_t idx = (size_t)grow * NCOL + gcol;
                    out[idx] = acc[m][n][j] + skip[idx];
                }
            }
    }
}

// ---------------- Flash attention (causal), QBLK=128, swapped-operand ----------------
// Round-8 structure verbatim (66 us measured) with ONE change: balanced stripe
// qmap {7,6,0,1,5,4,2,3} (co-resident stripe sets {7,0,5,2} / {6,1,4,3} both sum
// to 36 kt-iters per CU). Swapped QK^T -> lane holds S^T[t][q=lr]; softmax
// in-register (2 shfls); P routed via wave-private XOR-swizzled LDS dword scratch
// (swz=(lr&3)<<3); scattered 2B O stores (not BW-bound). bh->XCD binding via f&7.
__launch_bounds__(256, 4) __global__
    void attn_kernel(const unsigned short* __restrict__ q, const unsigned short* __restrict__ k,
                     const unsigned short* __restrict__ vt, unsigned short* __restrict__ o) {
    constexpr int S = 1024, D = 64;
    __shared__ unsigned short Ks[2][64 * 64];  // [t][d], chunk-swizzled
    __shared__ unsigned short Vs[2][64 * 64];  // [d][t], chunk-swizzled
    __shared__ unsigned Pls[4][16 * 32];       // per-wave P dwords, XOR-swizzled
    const int tid = threadIdx.x, lane = tid & 63, w = tid >> 6;
    const int lr = lane & 15, lg = lane >> 4;
    // balanced stripes of 128 blocks; bh->XCD binding via f&7.
    const int f = blockIdx.x;  // 0..1023
    constexpr int qmap[8] = {7, 6, 0, 1, 5, 4, 2, 3};
    const int qb = qmap[f >> 7];
    const int bh = (f & 7) * 16 + ((f >> 3) & 15);
    const int qs = qb * 128;
    const size_t base = (size_t)bh * (S * D);
    const int wrow0 = qs + w * 32;

    short8 qf[2][2];
#pragma unroll
    for (int m = 0; m < 2; ++m) {
        const unsigned short* qp = q + base + (size_t)(wrow0 + m * 16 + lr) * D;
        qf[m][0] = *(const short8*)(qp + lg * 8);
        qf[m][1] = *(const short8*)(qp + 32 + lg * 8);
    }

    f32x4 of[2][4] = {};  // O[q = wrow0 + m*16 + lg*4 + j][d = 16*n2 + lr]
    float mrun[2] = {-1e30f, -1e30f};
    float lrun[2] = {0.f, 0.f};  // per-lane partial (own t-subset); reduced at end

    const int nkt = 2 * qb + 2;

    auto stageK = [&](int buf, int kt) {
#pragma unroll
        for (int i = 0; i < 2; ++i) {
            int seg = i * 256 + tid;
            int row = seg >> 3, c8 = (seg & 7) ^ (row & 7);
            gl_lds16(k + base + (size_t)(kt * 64 + row) * D + c8 * 8,
                     &Ks[buf][(i * 256 + w * 64) * 8]);
        }
    };
    auto stageV = [&](int buf, int kt) {
#pragma unroll
        for (int i = 0; i < 2; ++i) {
            int seg = i * 256 + tid;
            int row = seg >> 3, c8 = (seg & 7) ^ (row & 7);
            gl_lds16(vt + base + (size_t)row * S + kt * 64 + c8 * 8,
                     &Vs[buf][(i * 256 + w * 64) * 8]);
        }
    };

    unsigned* Pw = &Pls[w][0];
    const int swz = (lr & 3) << 3;

    stageK(0, 0);
    stageV(0, 0);
    __syncthreads();

    for (int kt = 0; kt < nkt; ++kt) {
        const int b = kt & 1;
        if (kt + 1 < nkt) {
            stageK(b ^ 1, kt + 1);
            stageV(b ^ 1, kt + 1);
        }

        if (kt * 64 <= wrow0 + 31) {  // wave-uniform: this wave has unmasked rows
            // Swapped QK^T: sf[m][n][j] = S^T[t = kt*64+16n+lg*4+j][q = wrow0+m*16+lr]
            f32x4 sf[2][4] = {};
            __builtin_amdgcn_s_setprio(1);
#pragma unroll
            for (int n = 0; n < 4; ++n) {
                const int r = n * 16 + lr;
#pragma unroll
                for (int kkc = 0; kkc < 2; ++kkc) {
                    short8 kf = *(const short8*)&Ks[b][r * 64 + (((kkc * 4 + lg) ^ (lr & 7)) * 8)];
#pragma unroll
                    for (int m = 0; m < 2; ++m) sf[m][n] = MFMA16(kf, qf[m][kkc], sf[m][n]);
                }
            }
            __builtin_amdgcn_s_setprio(0);

            if (kt * 64 + 63 > wrow0) {  // tile overlaps diagonal for this wave
#pragma unroll
                for (int m = 0; m < 2; ++m)
#pragma unroll
                    for (int n = 0; n < 4; ++n)
#pragma unroll
                        for (int j = 0; j < 4; ++j) {
                            int t = kt * 64 + 16 * n + lg * 4 + j;
                            int qr = wrow0 + m * 16 + lr;
                            if (t > qr) sf[m][n][j] = -1e30f;
                        }
            }

#pragma unroll
            for (int m = 0; m < 2; ++m) {
                // in-lane max over 16 t-values, then 2 shfls across the 4 lanes sharing q
                float mx = -1e30f;
#pragma unroll
                for (int n = 0; n < 4; ++n)
                    mx = fmaxf(mx, fmaxf(fmaxf(sf[m][n][0], sf[m][n][1]),
                                         fmaxf(sf[m][n][2], sf[m][n][3])));
                mx = fmaxf(mx, __shfl_xor(mx, 16));
                mx = fmaxf(mx, __shfl_xor(mx, 32));

                if (__any(mx > mrun[m] + 8.0f)) {
                    float newm = fmaxf(mrun[m], mx);
                    float sc = __builtin_amdgcn_exp2f(mrun[m] - newm);
                    mrun[m] = newm;
                    float psum = 0.f;
#pragma unroll
                    for (int n = 0; n < 4; ++n)
#pragma unroll
                        for (int j = 0; j < 4; ++j) {
                            float p = __builtin_amdgcn_exp2f(sf[m][n][j] - newm);
                            sf[m][n][j] = p;
                            psum += p;
                        }
                    lrun[m] = lrun[m] * sc + psum;
#pragma unroll
                    for (int n2 = 0; n2 < 4; ++n2) of[m][n2] *= sc;
                } else {
                    float mo = mrun[m];
                    float psum = 0.f;
#pragma unroll
                    for (int n = 0; n < 4; ++n)
#pragma unroll
                        for (int j = 0; j < 4; ++j) {
                            float p = __builtin_amdgcn_exp2f(sf[m][n][j] - mo);
                            sf[m][n][j] = p;
                            psum += p;
                        }
                    lrun[m] += psum;
                }
            }

            // P -> PV A-frags through wave-private LDS dwords.
            // Write: dword tp = 8n+2lg+w2 holds t = {2tp, 2tp+1} for q-row lr.
            // Read:  A-frag k-layout t = kkc*32 + 8lg + j  -> dwords tp = kkc*16+4lg+{0..3}.
            short8 pa[2][2];  // [m][kkc]
#pragma unroll
            for (int m = 0; m < 2; ++m) {
                unsigned Dk[4][2];
#pragma unroll
                for (int n = 0; n < 4; ++n)
#pragma unroll
                    for (int w2 = 0; w2 < 2; ++w2)
                        Dk[n][w2] = (unsigned)f2b(sf[m][n][2 * w2]) |
                                    ((unsigned)f2b(sf[m][n][2 * w2 + 1]) << 16);
#pragma unroll
                for (int n = 0; n < 4; ++n)
#pragma unroll
                    for (int w2 = 0; w2 < 2; ++w2)
                        Pw[lr * 32 + ((8 * n + 2 * lg + w2) ^ swz)] = Dk[n][w2];
#pragma unroll
                for (int kkc = 0; kkc < 2; ++kkc)
                    pa[m][kkc] = *(const short8*)&Pw[lr * 32 + ((kkc * 16 + 4 * lg) ^ swz)];
            }

            // PV: O[q][d] += P[q][t] * V[t][d]; V^T-frag read identical to K-frag
            __builtin_amdgcn_s_setprio(1);
#pragma unroll
            for (int kkc = 0; kkc < 2; ++kkc) {
#pragma unroll
                for (int n2 = 0; n2 < 4; ++n2) {
                    const int r = n2 * 16 + lr;
                    short8 bv = *(const short8*)&Vs[b][r * 64 + (((kkc * 4 + lg) ^ (lr & 7)) * 8)];
#pragma unroll
                    for (int m = 0; m < 2; ++m) of[m][n2] = MFMA16(pa[m][kkc], bv, of[m][n2]);
                }
            }
            __builtin_amdgcn_s_setprio(0);
        }

        __syncthreads();
    }

    // final l per q-row, redistributed through the wave-private scratch
    float* Lw = (float*)&Pls[w][0];
#pragma unroll
    for (int m = 0; m < 2; ++m) {
        float l = lrun[m];
        l += __shfl_xor(l, 16);
        l += __shfl_xor(l, 32);
        Lw[m * 16 + lr] = l;  // all lg write the same value
    }
    const int bb = bh >> 4, h = bh & 15;
#pragma unroll
    for (int m = 0; m < 2; ++m)
#pragma unroll
        for (int j = 0; j < 4; ++j) {
            float inv = 1.f / Lw[m * 16 + lg * 4 + j];
            int srow = wrow0 + m * 16 + lg * 4 + j;
            size_t ob = ((size_t)(bb * 1024 + srow)) * 1024 + h * 64;
#pragma unroll
            for (int n2 = 0; n2 < 4; ++n2)
                o[ob + n2 * 16 + lr] = f2b(of[m][n2][j] * inv);
        }
}

extern "C" void kernel_launch(void* const* d_in, const int* in_sizes, int n_in, void* d_out,
                              int out_size, void* d_ws, size_t ws_size, hipStream_t stream) {
    const float* x = (const float*)d_in[0];
    const float* scale = (const float*)d_in[1];
    const float* w_qkv = (const float*)d_in[2];
    const float* w_out = (const float*)d_in[3];
    const float* theta = (const float*)d_in[4];
    float* out = (float*)d_out;

    char* p = (char*)d_ws;
    unsigned short* xn = (unsigned short*)p;      p += (size_t)8192 * 1024 * 2;
    unsigned short* wqb = (unsigned short*)p;     p += (size_t)3072 * 1024 * 2;
    unsigned short* wob = (unsigned short*)p;     p += (size_t)1024 * 1024 * 2;
    unsigned short* qb_ = (unsigned short*)p;     p += (size_t)128 * 1024 * 64 * 2;
    unsigned short* kb_ = (unsigned short*)p;     p += (size_t)128 * 1024 * 64 * 2;
    unsigned short* vb_ = (unsigned short*)p;     p += (size_t)128 * 1024 * 64 * 2;  // V^T (B,H,D,S)
    unsigned short* ob_ = (unsigned short*)p;     p += (size_t)8192 * 1024 * 2;

    rmsnorm_kernel<<<8192, 256, 0, stream>>>(x, scale, xn);
    f2b_kernel<<<3072, 256, 0, stream>>>(w_qkv, wqb, 786432);
    f2b_kernel<<<1024, 256, 0, stream>>>(w_out, wob, 262144);
    gemm_bt<0><<<1536, 256, 0, stream>>>(xn, wqb, qb_, kb_, vb_, nullptr, nullptr, theta);
    attn_kernel<<<1024, 256, 0, stream>>>(qb_, kb_, vb_, ob_);
    gemm_bt<1><<<512, 256, 0, stream>>>(ob_, wob, nullptr, nullptr, nullptr, x, out, nullptr);
}

// Round 14
// 157.368 us; speedup vs baseline: 1.1834x; 1.0140x over previous
//
#include <hip/hip_runtime.h>
#include <hip/hip_bf16.h>
#include <cstdint>

typedef short short8 __attribute__((ext_vector_type(8)));
typedef float f32x4 __attribute__((ext_vector_type(4)));

#define MFMA16(a, b, c) __builtin_amdgcn_mfma_f32_16x16x32_bf16((a), (b), (c), 0, 0, 0)

__device__ __forceinline__ unsigned short f2b(float f) {
    __hip_bfloat16 h = __float2bfloat16(f);
    return __builtin_bit_cast(unsigned short, h);
}

__device__ __forceinline__ void gl_lds16(const void* g, void* l) {
    __builtin_amdgcn_global_load_lds((const __attribute__((address_space(1))) void*)g,
                                     (__attribute__((address_space(3))) void*)l, 16, 0, 0);
}

// (1/8) * log2(e): QK^T scores land in log2 domain -> bare v_exp_f32 softmax
#define QSC 0.18033688011112042f

// ---------------- RMSNorm: fp32 x -> bf16 xn ----------------
__global__ void rmsnorm_kernel(const float* __restrict__ x, const float* __restrict__ scale,
                               unsigned short* __restrict__ xn) {
    const int row = blockIdx.x;
    const int tid = threadIdx.x;
    const float4* xr = (const float4*)(x + (size_t)row * 1024);
    float4 vx = xr[tid];
    float ss = vx.x * vx.x + vx.y * vx.y + vx.z * vx.z + vx.w * vx.w;
#pragma unroll
    for (int m = 1; m < 64; m <<= 1) ss += __shfl_xor(ss, m);
    __shared__ float wsum[4];
    if ((tid & 63) == 0) wsum[tid >> 6] = ss;
    __syncthreads();
    float tot = wsum[0] + wsum[1] + wsum[2] + wsum[3];
    float rs = rsqrtf(tot * (1.0f / 1024.0f) + 1e-6f);
    const float4* sr = (const float4*)scale;
    float4 sv = sr[tid];
    ushort4 r;
    r.x = f2b(vx.x * sv.x * rs);
    r.y = f2b(vx.y * sv.y * rs);
    r.z = f2b(vx.z * sv.z * rs);
    r.w = f2b(vx.w * sv.w * rs);
    *(ushort4*)(xn + (size_t)row * 1024 + tid * 4) = r;
}

// ---------------- f32 -> bf16 convert ----------------
__global__ void f2b_kernel(const float* __restrict__ in, unsigned short* __restrict__ outp, int n4) {
    int i = blockIdx.x * 256 + threadIdx.x;
    if (i < n4) {
        float4 vv = ((const float4*)in)[i];
        ushort4 r;
        r.x = f2b(vv.x);
        r.y = f2b(vv.y);
        r.z = f2b(vv.z);
        r.w = f2b(vv.w);
        ((ushort4*)outp)[i] = r;
    }
}

// ---------------- GEMM C = A * B^T (A: MxK bf16 row-major, B: NxK bf16 row-major) ----
// m97 structure: single-buffered 32 KB LDS, XOR chunk-swizzle (conflict-free ds_read_b128),
// global_load_lds width-16 staging, 2 barriers per K-step, high occupancy.
// EPI 0: scatter qkv; RoPE fused for q,k (q scaled by QSC); v TRANSPOSED (B,H,D,S)
// EPI 1: out[m][n] = acc + skip[m][n]  (fp32)
constexpr int BM = 128, BN = 128, BK = 64, KDIM = 1024, NT = KDIM / BK;

template <int EPI>
__launch_bounds__(256, 4) __global__
    void gemm_bt(const unsigned short* __restrict__ A, const unsigned short* __restrict__ Bw,
                 unsigned short* __restrict__ qo, unsigned short* __restrict__ ko,
                 unsigned short* __restrict__ vo, const float* __restrict__ skip,
                 float* __restrict__ out, const float* __restrict__ theta) {
    __shared__ unsigned short As[BM * BK];
    __shared__ unsigned short Bs[BN * BK];
    const int tid = threadIdx.x;
    const int lane = tid & 63, w = tid >> 6;
    const int wr = w >> 1, wc = w & 1;
    const int lr = lane & 15, lg = lane >> 4;
    // XCD-aware bijective swizzle: each XCD gets 8 consecutive by-rows.
    constexpr int NBX = (EPI == 0) ? 24 : 8;
    const int f = blockIdx.x;
    const int xcd = f & 7, wloc = f >> 3;
    const int g = xcd * (NBX * 8) + wloc;
    const int bx = g % NBX, by = g / NBX;
    const int m0 = by * BM;
    const int n0 = bx * BN;
    const int NCOL = (EPI == 0) ? 3072 : 1024;

    f32x4 acc[4][4] = {};

    // LDS[row][slot] = global[row][chunk slot ^ (row&7)]  (16B chunks, 8 per row)
    auto stage = [&](int kt) {
        const int k0 = kt * BK;
#pragma unroll
        for (int i = 0; i < 4; ++i) {
            int seg = i * 256 + tid;
            int row = seg >> 3, c8 = (seg & 7) ^ (row & 7);
            gl_lds16(A + (size_t)(m0 + row) * KDIM + k0 + c8 * 8, &As[(i * 256 + w * 64) * 8]);
            gl_lds16(Bw + (size_t)(n0 + row) * KDIM + k0 + c8 * 8, &Bs[(i * 256 + w * 64) * 8]);
        }
    };

    for (int kt = 0; kt < NT; ++kt) {
        stage(kt);
        __syncthreads();
#pragma unroll
        for (int kkc = 0; kkc < 2; ++kkc) {
            short8 a[4], b[4];
            const int slot = ((kkc * 4 + lg) ^ (lr & 7)) * 8;
#pragma unroll
            for (int m = 0; m < 4; ++m)
                a[m] = *(const short8*)&As[(wr * 64 + m * 16 + lr) * BK + slot];
#pragma unroll
            for (int n = 0; n < 4; ++n)
                b[n] = *(const short8*)&Bs[(wc * 64 + n * 16 + lr) * BK + slot];
#pragma unroll
            for (int m = 0; m < 4; ++m)
#pragma unroll
                for (int n = 0; n < 4; ++n) acc[m][n] = MFMA16(a[m], b[n], acc[m][n]);
        }
        __syncthreads();
    }

    if (EPI == 0) {
        // whole (block, wc) group is one output tensor c and one head h
        const int colb = n0 + wc * 64;
        const int c = colb >> 10, h = (colb >> 6) & 15;
#pragma unroll
        for (int m = 0; m < 4; ++m) {
            int grow0 = m0 + wr * 64 + m * 16 + lg * 4;
            int b = grow0 >> 10, s0 = grow0 & 1023;
            if (c == 2) {
#pragma unroll
                for (int n = 0; n < 4; ++n) {
                    int d = n * 16 + lr;
                    ushort4 r;
                    r.x = f2b(acc[m][n][0]);
                    r.y = f2b(acc[m][n][1]);
                    r.z = f2b(acc[m][n][2]);
                    r.w = f2b(acc[m][n][3]);
                    *(ushort4*)&vo[(((size_t)(b * 16 + h)) * 64 + d) * 1024 + s0] = r;
                }
            } else {
                unsigned short* dst = (c == 0) ? qo : ko;
                float sc = (c == 0) ? QSC : 1.0f;
#pragma unroll
                for (int j = 0; j < 4; ++j) {
                    int s = s0 + j;
                    float th = theta[((s * 16 + h) << 4) + lr];
                    float sn, cs;
                    __sincosf(th, &sn, &cs);
                    float x1 = acc[m][0][j], x2 = acc[m][1][j];
                    size_t rowb = (((size_t)(b * 16 + h)) * 1024 + s) * 64;
                    dst[rowb + lr]      = f2b((x1 * cs - x2 * sn) * sc);
                    dst[rowb + 16 + lr] = f2b((x2 * cs + x1 * sn) * sc);
                    dst[rowb + 32 + lr] = f2b(acc[m][2][j] * sc);
                    dst[rowb + 48 + lr] = f2b(acc[m][3][j] * sc);
                }
            }
        }
    } else {
#pragma unroll
        for (int m = 0; m < 4; ++m)
#pragma unroll
            for (int n = 0; n < 4; ++n) {
                int gcol = n0 + wc * 64 + n * 16 + lr;
#pragma unroll
                for (int j = 0; j < 4; ++j) {
                    int grow = m0 + wr * 64 + m * 16 + lg * 4 + j;
                    size_t idx = (size_t)grow * NCOL + gcol;
                    out[idx] = acc[m][n][j] + skip[idx];
                }
            }
    }
}

// ---------------- Flash attention (causal), QBLK=256, 8 waves, swapped-operand ------
// q,k: (B,H,S,D) bf16 (q pre-scaled by QSC, rope applied).  vT: (B,H,D,S) bf16.
// o: (B,S,H*D) bf16. Per-wave inner loop identical to round-13 (32 q-rows/wave,
// swapped QK^T, in-register softmax, P via wave-private XOR-swizzled LDS scratch,
// scattered 2B O stores). Geometry change only: 8 waves share each staged K/V
// tile (256 q-rows per stage/barrier -> 44% fewer block-iters), 1 gl_lds per
// thread per tensor. Balanced stripes for 2-resident blocks: qmap4 {3,2,0,1}
// ({s0,s2}=20 iters = {s1,s3}); LPT heavy-first; bh->XCD binding via f&7.
__launch_bounds__(512, 4) __global__
    void attn_kernel(const unsigned short* __restrict__ q, const unsigned short* __restrict__ k,
                     const unsigned short* __restrict__ vt, unsigned short* __restrict__ o) {
    constexpr int S = 1024, D = 64;
    __shared__ unsigned short Ks[2][64 * 64];  // [t][d], chunk-swizzled
    __shared__ unsigned short Vs[2][64 * 64];  // [d][t], chunk-swizzled
    __shared__ unsigned Pls[8][16 * 32];       // per-wave P dwords, XOR-swizzled
    const int tid = threadIdx.x, lane = tid & 63, w = tid >> 6;  // w = 0..7
    const int lr = lane & 15, lg = lane >> 4;
    const int f = blockIdx.x;  // 0..511
    constexpr int qmap4[4] = {3, 2, 0, 1};
    const int qb = qmap4[f >> 7];
    const int bh = (f & 7) * 16 + ((f >> 3) & 15);
    const int qs = qb * 256;
    const size_t base = (size_t)bh * (S * D);
    const int wrow0 = qs + w * 32;

    short8 qf[2][2];
#pragma unroll
    for (int m = 0; m < 2; ++m) {
        const unsigned short* qp = q + base + (size_t)(wrow0 + m * 16 + lr) * D;
        qf[m][0] = *(const short8*)(qp + lg * 8);
        qf[m][1] = *(const short8*)(qp + 32 + lg * 8);
    }

    f32x4 of[2][4] = {};  // O[q = wrow0 + m*16 + lg*4 + j][d = 16*n2 + lr]
    float mrun[2] = {-1e30f, -1e30f};
    float lrun[2] = {0.f, 0.f};  // per-lane partial (own t-subset); reduced at end

    const int nkt = 4 * qb + 4;

    // one 16B chunk per thread per tensor: 512 threads x 16B = one 64x64 bf16 tile
    const int srow = tid >> 3, sc8 = (tid & 7) ^ (srow & 7);
    auto stageK = [&](int buf, int kt) {
        gl_lds16(k + base + (size_t)(kt * 64 + srow) * D + sc8 * 8, &Ks[buf][w * 512]);
    };
    auto stageV = [&](int buf, int kt) {
        gl_lds16(vt + base + (size_t)srow * S + kt * 64 + sc8 * 8, &Vs[buf][w * 512]);
    };

    unsigned* Pw = &Pls[w][0];
    const int swz = (lr & 3) << 3;

    stageK(0, 0);
    stageV(0, 0);
    __syncthreads();

    for (int kt = 0; kt < nkt; ++kt) {
        const int b = kt & 1;
        if (kt + 1 < nkt) {
            stageK(b ^ 1, kt + 1);
            stageV(b ^ 1, kt + 1);
        }

        if (kt * 64 <= wrow0 + 31) {  // wave-uniform: this wave has unmasked rows
            // Swapped QK^T: sf[m][n][j] = S^T[t = kt*64+16n+lg*4+j][q = wrow0+m*16+lr]
            f32x4 sf[2][4] = {};
            __builtin_amdgcn_s_setprio(1);
#pragma unroll
            for (int n = 0; n < 4; ++n) {
                const int r = n * 16 + lr;
#pragma unroll
                for (int kkc = 0; kkc < 2; ++kkc) {
                    short8 kf = *(const short8*)&Ks[b][r * 64 + (((kkc * 4 + lg) ^ (lr & 7)) * 8)];
#pragma unroll
                    for (int m = 0; m < 2; ++m) sf[m][n] = MFMA16(kf, qf[m][kkc], sf[m][n]);
                }
            }
            __builtin_amdgcn_s_setprio(0);

            if (kt * 64 + 63 > wrow0) {  // tile overlaps diagonal for this wave
#pragma unroll
                for (int m = 0; m < 2; ++m)
#pragma unroll
                    for (int n = 0; n < 4; ++n)
#pragma unroll
                        for (int j = 0; j < 4; ++j) {
                            int t = kt * 64 + 16 * n + lg * 4 + j;
                            int qr = wrow0 + m * 16 + lr;
                            if (t > qr) sf[m][n][j] = -1e30f;
                        }
            }

#pragma unroll
            for (int m = 0; m < 2; ++m) {
                // in-lane max over 16 t-values, then 2 shfls across the 4 lanes sharing q
                float mx = -1e30f;
#pragma unroll
                for (int n = 0; n < 4; ++n)
                    mx = fmaxf(mx, fmaxf(fmaxf(sf[m][n][0], sf[m][n][1]),
                                         fmaxf(sf[m][n][2], sf[m][n][3])));
                mx = fmaxf(mx, __shfl_xor(mx, 16));
                mx = fmaxf(mx, __shfl_xor(mx, 32));

                if (__any(mx > mrun[m] + 8.0f)) {
                    float newm = fmaxf(mrun[m], mx);
                    float sc = __builtin_amdgcn_exp2f(mrun[m] - newm);
                    mrun[m] = newm;
                    float psum = 0.f;
#pragma unroll
                    for (int n = 0; n < 4; ++n)
#pragma unroll
                        for (int j = 0; j < 4; ++j) {
                            float p = __builtin_amdgcn_exp2f(sf[m][n][j] - newm);
                            sf[m][n][j] = p;
                            psum += p;
                        }
                    lrun[m] = lrun[m] * sc + psum;
#pragma unroll
                    for (int n2 = 0; n2 < 4; ++n2) of[m][n2] *= sc;
                } else {
                    float mo = mrun[m];
                    float psum = 0.f;
#pragma unroll
                    for (int n = 0; n < 4; ++n)
#pragma unroll
                        for (int j = 0; j < 4; ++j) {
                            float p = __builtin_amdgcn_exp2f(sf[m][n][j] - mo);
                            sf[m][n][j] = p;
                            psum += p;
                        }
                    lrun[m] += psum;
                }
            }

            // P -> PV A-frags through wave-private LDS dwords.
            // Write: dword tp = 8n+2lg+w2 holds t = {2tp, 2tp+1} for q-row lr.
            // Read:  A-frag k-layout t = kkc*32 + 8lg + j  -> dwords tp = kkc*16+4lg+{0..3}.
            short8 pa[2][2];  // [m][kkc]
#pragma unroll
            for (int m = 0; m < 2; ++m) {
                unsigned Dk[4][2];
#pragma unroll
                for (int n = 0; n < 4; ++n)
#pragma unroll
                    for (int w2 = 0; w2 < 2; ++w2)
                        Dk[n][w2] = (unsigned)f2b(sf[m][n][2 * w2]) |
                                    ((unsigned)f2b(sf[m][n][2 * w2 + 1]) << 16);
#pragma unroll
                for (int n = 0; n < 4; ++n)
#pragma unroll
                    for (int w2 = 0; w2 < 2; ++w2)
                        Pw[lr * 32 + ((8 * n + 2 * lg + w2) ^ swz)] = Dk[n][w2];
#pragma unroll
                for (int kkc = 0; kkc < 2; ++kkc)
                    pa[m][kkc] = *(const short8*)&Pw[lr * 32 + ((kkc * 16 + 4 * lg) ^ swz)];
            }

            // PV: O[q][d] += P[q][t] * V[t][d]; V^T-frag read identical to K-frag
            __builtin_amdgcn_s_setprio(1);
#pragma unroll
            for (int kkc = 0; kkc < 2; ++kkc) {
#pragma unroll
                for (int n2 = 0; n2 < 4; ++n2) {
                    const int r = n2 * 16 + lr;
                    short8 bv = *(const short8*)&Vs[b][r * 64 + (((kkc * 4 + lg) ^ (lr & 7)) * 8)];
#pragma unroll
                    for (int m = 0; m < 2; ++m) of[m][n2] = MFMA16(pa[m][kkc], bv, of[m][n2]);
                }
            }
            __builtin_amdgcn_s_setprio(0);
        }

        __syncthreads();
    }

    // final l per q-row, redistributed through the wave-private scratch
    float* Lw = (float*)&Pls[w][0];
#pragma unroll
    for (int m = 0; m < 2; ++m) {
        float l = lrun[m];
        l += __shfl_xor(l, 16);
        l += __shfl_xor(l, 32);
        Lw[m * 16 + lr] = l;  // all lg write the same value
    }
    const int bb = bh >> 4, h = bh & 15;
#pragma unroll
    for (int m = 0; m < 2; ++m)
#pragma unroll
        for (int j = 0; j < 4; ++j) {
            float inv = 1.f / Lw[m * 16 + lg * 4 + j];
            int orow = wrow0 + m * 16 + lg * 4 + j;
            size_t ob = ((size_t)(bb * 1024 + orow)) * 1024 + h * 64;
#pragma unroll
            for (int n2 = 0; n2 < 4; ++n2)
                o[ob + n2 * 16 + lr] = f2b(of[m][n2][j] * inv);
        }
}

extern "C" void kernel_launch(void* const* d_in, const int* in_sizes, int n_in, void* d_out,
                              int out_size, void* d_ws, size_t ws_size, hipStream_t stream) {
    const float* x = (const float*)d_in[0];
    const float* scale = (const float*)d_in[1];
    const float* w_qkv = (const float*)d_in[2];
    const float* w_out = (const float*)d_in[3];
    const float* theta = (const float*)d_in[4];
    float* out = (float*)d_out;

    char* p = (char*)d_ws;
    unsigned short* xn = (unsigned short*)p;      p += (size_t)8192 * 1024 * 2;
    unsigned short* wqb = (unsigned short*)p;     p += (size_t)3072 * 1024 * 2;
    unsigned short* wob = (unsigned short*)p;     p += (size_t)1024 * 1024 * 2;
    unsigned short* qb_ = (unsigned short*)p;     p += (size_t)128 * 1024 * 64 * 2;
    unsigned short* kb_ = (unsigned short*)p;     p += (size_t)128 * 1024 * 64 * 2;
    unsigned short* vb_ = (unsigned short*)p;     p += (size_t)128 * 1024 * 64 * 2;  // V^T (B,H,D,S)
    unsigned short* ob_ = (unsigned short*)p;     p += (size_t)8192 * 1024 * 2;

    rmsnorm_kernel<<<8192, 256, 0, stream>>>(x, scale, xn);
    f2b_kernel<<<3072, 256, 0, stream>>>(w_qkv, wqb, 786432);
    f2b_kernel<<<1024, 256, 0, stream>>>(w_out, wob, 262144);
    gemm_bt<0><<<1536, 256, 0, stream>>>(xn, wqb, qb_, kb_, vb_, nullptr, nullptr, theta);
    attn_kernel<<<512, 512, 0, stream>>>(qb_, kb_, vb_, ob_);
    gemm_bt<1><<<512, 256, 0, stream>>>(ob_, wob, nullptr, nullptr, nullptr, x, out, nullptr);
}

// Round 15
// 151.852 us; speedup vs baseline: 1.2264x; 1.0363x over previous
//
#include <hip/hip_runtime.h>
#include <hip/hip_bf16.h>
#include <cstdint>

typedef short short8 __attribute__((ext_vector_type(8)));
typedef float f32x4 __attribute__((ext_vector_type(4)));
typedef unsigned uint4v __attribute__((ext_vector_type(4)));

#define MFMA16(a, b, c) __builtin_amdgcn_mfma_f32_16x16x32_bf16((a), (b), (c), 0, 0, 0)

__device__ __forceinline__ unsigned short f2b(float f) {
    __hip_bfloat16 h = __float2bfloat16(f);
    return __builtin_bit_cast(unsigned short, h);
}

__device__ __forceinline__ void gl_lds16(const void* g, void* l) {
    __builtin_amdgcn_global_load_lds((const __attribute__((address_space(1))) void*)g,
                                     (__attribute__((address_space(3))) void*)l, 16, 0, 0);
}

// (1/8) * log2(e): QK^T scores land in log2 domain -> bare v_exp_f32 softmax
#define QSC 0.18033688011112042f

// ---------------- RMSNorm: fp32 x -> bf16 xn ----------------
__global__ void rmsnorm_kernel(const float* __restrict__ x, const float* __restrict__ scale,
                               unsigned short* __restrict__ xn) {
    const int row = blockIdx.x;
    const int tid = threadIdx.x;
    const float4* xr = (const float4*)(x + (size_t)row * 1024);
    float4 vx = xr[tid];
    float ss = vx.x * vx.x + vx.y * vx.y + vx.z * vx.z + vx.w * vx.w;
#pragma unroll
    for (int m = 1; m < 64; m <<= 1) ss += __shfl_xor(ss, m);
    __shared__ float wsum[4];
    if ((tid & 63) == 0) wsum[tid >> 6] = ss;
    __syncthreads();
    float tot = wsum[0] + wsum[1] + wsum[2] + wsum[3];
    float rs = rsqrtf(tot * (1.0f / 1024.0f) + 1e-6f);
    const float4* sr = (const float4*)scale;
    float4 sv = sr[tid];
    ushort4 r;
    r.x = f2b(vx.x * sv.x * rs);
    r.y = f2b(vx.y * sv.y * rs);
    r.z = f2b(vx.z * sv.z * rs);
    r.w = f2b(vx.w * sv.w * rs);
    *(ushort4*)(xn + (size_t)row * 1024 + tid * 4) = r;
}

// ---------------- f32 -> bf16 convert ----------------
__global__ void f2b_kernel(const float* __restrict__ in, unsigned short* __restrict__ outp, int n4) {
    int i = blockIdx.x * 256 + threadIdx.x;
    if (i < n4) {
        float4 vv = ((const float4*)in)[i];
        ushort4 r;
        r.x = f2b(vv.x);
        r.y = f2b(vv.y);
        r.z = f2b(vv.z);
        r.w = f2b(vv.w);
        ((ushort4*)outp)[i] = r;
    }
}

// ---------------- GEMM C = A * B^T (A: MxK bf16 row-major, B: NxK bf16 row-major) ----
// m97 structure: single-buffered 32 KB LDS, XOR chunk-swizzle (conflict-free ds_read_b128),
// global_load_lds width-16 staging, 2 barriers per K-step, high occupancy.
// EPI 0: scatter qkv; RoPE fused for q,k (q scaled by QSC); v TRANSPOSED (B,H,D,S)
// EPI 1: out[m][n] = acc + skip[m][n]  (fp32)
constexpr int BM = 128, BN = 128, BK = 64, KDIM = 1024, NT = KDIM / BK;

template <int EPI>
__launch_bounds__(256, 4) __global__
    void gemm_bt(const unsigned short* __restrict__ A, const unsigned short* __restrict__ Bw,
                 unsigned short* __restrict__ qo, unsigned short* __restrict__ ko,
                 unsigned short* __restrict__ vo, const float* __restrict__ skip,
                 float* __restrict__ out, const float* __restrict__ theta) {
    __shared__ unsigned short As[BM * BK];
    __shared__ unsigned short Bs[BN * BK];
    const int tid = threadIdx.x;
    const int lane = tid & 63, w = tid >> 6;
    const int wr = w >> 1, wc = w & 1;
    const int lr = lane & 15, lg = lane >> 4;
    // XCD-aware bijective swizzle: each XCD gets 8 consecutive by-rows.
    constexpr int NBX = (EPI == 0) ? 24 : 8;
    const int f = blockIdx.x;
    const int xcd = f & 7, wloc = f >> 3;
    const int g = xcd * (NBX * 8) + wloc;
    const int bx = g % NBX, by = g / NBX;
    const int m0 = by * BM;
    const int n0 = bx * BN;
    const int NCOL = (EPI == 0) ? 3072 : 1024;

    f32x4 acc[4][4] = {};

    // LDS[row][slot] = global[row][chunk slot ^ (row&7)]  (16B chunks, 8 per row)
    auto stage = [&](int kt) {
        const int k0 = kt * BK;
#pragma unroll
        for (int i = 0; i < 4; ++i) {
            int seg = i * 256 + tid;
            int row = seg >> 3, c8 = (seg & 7) ^ (row & 7);
            gl_lds16(A + (size_t)(m0 + row) * KDIM + k0 + c8 * 8, &As[(i * 256 + w * 64) * 8]);
            gl_lds16(Bw + (size_t)(n0 + row) * KDIM + k0 + c8 * 8, &Bs[(i * 256 + w * 64) * 8]);
        }
    };

    for (int kt = 0; kt < NT; ++kt) {
        stage(kt);
        __syncthreads();
#pragma unroll
        for (int kkc = 0; kkc < 2; ++kkc) {
            short8 a[4], b[4];
            const int slot = ((kkc * 4 + lg) ^ (lr & 7)) * 8;
#pragma unroll
            for (int m = 0; m < 4; ++m)
                a[m] = *(const short8*)&As[(wr * 64 + m * 16 + lr) * BK + slot];
#pragma unroll
            for (int n = 0; n < 4; ++n)
                b[n] = *(const short8*)&Bs[(wc * 64 + n * 16 + lr) * BK + slot];
#pragma unroll
            for (int m = 0; m < 4; ++m)
#pragma unroll
                for (int n = 0; n < 4; ++n) acc[m][n] = MFMA16(a[m], b[n], acc[m][n]);
        }
        __syncthreads();
    }

    if (EPI == 0) {
        // whole (block, wc) group is one output tensor c and one head h
        const int colb = n0 + wc * 64;
        const int c = colb >> 10, h = (colb >> 6) & 15;
#pragma unroll
        for (int m = 0; m < 4; ++m) {
            int grow0 = m0 + wr * 64 + m * 16 + lg * 4;
            int b = grow0 >> 10, s0 = grow0 & 1023;
            if (c == 2) {
#pragma unroll
                for (int n = 0; n < 4; ++n) {
                    int d = n * 16 + lr;
                    ushort4 r;
                    r.x = f2b(acc[m][n][0]);
                    r.y = f2b(acc[m][n][1]);
                    r.z = f2b(acc[m][n][2]);
                    r.w = f2b(acc[m][n][3]);
                    *(ushort4*)&vo[(((size_t)(b * 16 + h)) * 64 + d) * 1024 + s0] = r;
                }
            } else {
                unsigned short* dst = (c == 0) ? qo : ko;
                float sc = (c == 0) ? QSC : 1.0f;
#pragma unroll
                for (int j = 0; j < 4; ++j) {
                    int s = s0 + j;
                    float th = theta[((s * 16 + h) << 4) + lr];
                    float sn, cs;
                    __sincosf(th, &sn, &cs);
                    float x1 = acc[m][0][j], x2 = acc[m][1][j];
                    size_t rowb = (((size_t)(b * 16 + h)) * 1024 + s) * 64;
                    dst[rowb + lr]      = f2b((x1 * cs - x2 * sn) * sc);
                    dst[rowb + 16 + lr] = f2b((x2 * cs + x1 * sn) * sc);
                    dst[rowb + 32 + lr] = f2b(acc[m][2][j] * sc);
                    dst[rowb + 48 + lr] = f2b(acc[m][3][j] * sc);
                }
            }
        }
    } else {
#pragma unroll
        for (int m = 0; m < 4; ++m)
#pragma unroll
            for (int n = 0; n < 4; ++n) {
                int gcol = n0 + wc * 64 + n * 16 + lr;
#pragma unroll
                for (int j = 0; j < 4; ++j) {
                    int grow = m0 + wr * 64 + m * 16 + lg * 4 + j;
                    size_t idx = (size_t)grow * NCOL + gcol;
                    out[idx] = acc[m][n][j] + skip[idx];
                }
            }
    }
}

// ---------------- Flash attention (causal), QBLK=256, 8 waves, swapped-operand ------
// q,k: (B,H,S,D) bf16 (q pre-scaled by QSC, rope applied).  vT: (B,H,D,S) bf16.
// o: (B,S,H*D) bf16. Round-14 structure with ONE change: P routed to the PV
// A-fragment via v_permlane32/16_swap in-register transpose (2 VALU ops per
// exchange; bit-mapping HW-proven by the round-6 shfl_xor implementation) —
// no LDS round-trip, no lgkm waits, no bank conflicts. vdst/src order: first
// operand's UPPER lanes swap with second's LOWER lanes -> vdst = r=0 member.
__launch_bounds__(512, 4) __global__
    void attn_kernel(const unsigned short* __restrict__ q, const unsigned short* __restrict__ k,
                     const unsigned short* __restrict__ vt, unsigned short* __restrict__ o) {
    constexpr int S = 1024, D = 64;
    __shared__ unsigned short Ks[2][64 * 64];  // [t][d], chunk-swizzled
    __shared__ unsigned short Vs[2][64 * 64];  // [d][t], chunk-swizzled
    __shared__ float Lls[8][32];               // per-wave final-l redistribution
    const int tid = threadIdx.x, lane = tid & 63, w = tid >> 6;  // w = 0..7
    const int lr = lane & 15, lg = lane >> 4;
    const int f = blockIdx.x;  // 0..511
    constexpr int qmap4[4] = {3, 2, 0, 1};
    const int qb = qmap4[f >> 7];
    const int bh = (f & 7) * 16 + ((f >> 3) & 15);
    const int qs = qb * 256;
    const size_t base = (size_t)bh * (S * D);
    const int wrow0 = qs + w * 32;

    short8 qf[2][2];
#pragma unroll
    for (int m = 0; m < 2; ++m) {
        const unsigned short* qp = q + base + (size_t)(wrow0 + m * 16 + lr) * D;
        qf[m][0] = *(const short8*)(qp + lg * 8);
        qf[m][1] = *(const short8*)(qp + 32 + lg * 8);
    }

    f32x4 of[2][4] = {};  // O[q = wrow0 + m*16 + lg*4 + j][d = 16*n2 + lr]
    float mrun[2] = {-1e30f, -1e30f};
    float lrun[2] = {0.f, 0.f};  // per-lane partial (own t-subset); reduced at end

    const int nkt = 4 * qb + 4;

    // one 16B chunk per thread per tensor: 512 threads x 16B = one 64x64 bf16 tile
    const int srow = tid >> 3, sc8 = (tid & 7) ^ (srow & 7);
    auto stageK = [&](int buf, int kt) {
        gl_lds16(k + base + (size_t)(kt * 64 + srow) * D + sc8 * 8, &Ks[buf][w * 512]);
    };
    auto stageV = [&](int buf, int kt) {
        gl_lds16(vt + base + (size_t)srow * S + kt * 64 + sc8 * 8, &Vs[buf][w * 512]);
    };

    stageK(0, 0);
    stageV(0, 0);
    __syncthreads();

    for (int kt = 0; kt < nkt; ++kt) {
        const int b = kt & 1;
        if (kt + 1 < nkt) {
            stageK(b ^ 1, kt + 1);
            stageV(b ^ 1, kt + 1);
        }

        if (kt * 64 <= wrow0 + 31) {  // wave-uniform: this wave has unmasked rows
            // Swapped QK^T: sf[m][n][j] = S^T[t = kt*64+16n+lg*4+j][q = wrow0+m*16+lr]
            f32x4 sf[2][4] = {};
            __builtin_amdgcn_s_setprio(1);
#pragma unroll
            for (int n = 0; n < 4; ++n) {
                const int r = n * 16 + lr;
#pragma unroll
                for (int kkc = 0; kkc < 2; ++kkc) {
                    short8 kf = *(const short8*)&Ks[b][r * 64 + (((kkc * 4 + lg) ^ (lr & 7)) * 8)];
#pragma unroll
                    for (int m = 0; m < 2; ++m) sf[m][n] = MFMA16(kf, qf[m][kkc], sf[m][n]);
                }
            }
            __builtin_amdgcn_s_setprio(0);

            if (kt * 64 + 63 > wrow0) {  // tile overlaps diagonal for this wave
#pragma unroll
                for (int m = 0; m < 2; ++m)
#pragma unroll
                    for (int n = 0; n < 4; ++n)
#pragma unroll
                        for (int j = 0; j < 4; ++j) {
                            int t = kt * 64 + 16 * n + lg * 4 + j;
                            int qr = wrow0 + m * 16 + lr;
                            if (t > qr) sf[m][n][j] = -1e30f;
                        }
            }

#pragma unroll
            for (int m = 0; m < 2; ++m) {
                // in-lane max over 16 t-values, then 2 shfls across the 4 lanes sharing q
                float mx = -1e30f;
#pragma unroll
                for (int n = 0; n < 4; ++n)
                    mx = fmaxf(mx, fmaxf(fmaxf(sf[m][n][0], sf[m][n][1]),
                                         fmaxf(sf[m][n][2], sf[m][n][3])));
                mx = fmaxf(mx, __shfl_xor(mx, 16));
                mx = fmaxf(mx, __shfl_xor(mx, 32));

                if (__any(mx > mrun[m] + 8.0f)) {
                    float newm = fmaxf(mrun[m], mx);
                    float sc = __builtin_amdgcn_exp2f(mrun[m] - newm);
                    mrun[m] = newm;
                    float psum = 0.f;
#pragma unroll
                    for (int n = 0; n < 4; ++n)
#pragma unroll
                        for (int j = 0; j < 4; ++j) {
                            float p = __builtin_amdgcn_exp2f(sf[m][n][j] - newm);
                            sf[m][n][j] = p;
                            psum += p;
                        }
                    lrun[m] = lrun[m] * sc + psum;
#pragma unroll
                    for (int n2 = 0; n2 < 4; ++n2) of[m][n2] *= sc;
                } else {
                    float mo = mrun[m];
                    float psum = 0.f;
#pragma unroll
                    for (int n = 0; n < 4; ++n)
#pragma unroll
                        for (int j = 0; j < 4; ++j) {
                            float p = __builtin_amdgcn_exp2f(sf[m][n][j] - mo);
                            sf[m][n][j] = p;
                            psum += p;
                        }
                    lrun[m] += psum;
                }
            }

            // P -> PV A-frags via permlane32/16_swap in-register transpose (no LDS).
            // Source dword Dk[n][w2] holds t-pair tp = 8n + 2lg + w2 (lo = even t), q = lr.
            // tp bits: [0]=w2 [1]=lane-b4 [2]=lane-b5 [3]=n0 [4]=n1.
            // Target A-frag: lane-b4=tp2, lane-b5=tp3, dword dd=(tp1,tp0), kkc=tp4.
            // xch32 (lane-b5 <-> n0): permlane32_swap(vdst=X0(r=0), src=X1(r=1));
            // xch16 (lane-b4 <-> pair-slot): permlane16_swap(vdst=X0, src=X1).
            // Mapping identical to the round-6 shfl_xor version (HW-verified).
            short8 pa[2][2];  // [m][kkc]
#pragma unroll
            for (int m = 0; m < 2; ++m) {
                unsigned Dk[4][2];
#pragma unroll
                for (int n = 0; n < 4; ++n)
#pragma unroll
                    for (int w2 = 0; w2 < 2; ++w2)
                        Dk[n][w2] = (unsigned)f2b(sf[m][n][2 * w2]) |
                                    ((unsigned)f2b(sf[m][n][2 * w2 + 1]) << 16);
#pragma unroll
                for (int n1 = 0; n1 < 2; ++n1) {
                    unsigned fr[4];
#pragma unroll
                    for (int w2 = 0; w2 < 2; ++w2) {
                        unsigned X0 = Dk[2 * n1][w2];      // r=0 (n0=0)
                        unsigned X1 = Dk[2 * n1 + 1][w2];  // r=1 (n0=1)
                        asm("v_permlane32_swap_b32 %0, %1" : "+v"(X0), "+v"(X1));
                        asm("v_permlane16_swap_b32 %0, %1" : "+v"(X0), "+v"(X1));
                        fr[w2] = X0;      // dd = w2
                        fr[2 + w2] = X1;  // dd = 2 + w2
                    }
                    uint4v t4 = {fr[0], fr[1], fr[2], fr[3]};
                    pa[m][n1] = __builtin_bit_cast(short8, t4);
                }
            }

            // PV: O[q][d] += P[q][t] * V[t][d]; V^T-frag read identical to K-frag
            __builtin_amdgcn_s_setprio(1);
#pragma unroll
            for (int kkc = 0; kkc < 2; ++kkc) {
#pragma unroll
                for (int n2 = 0; n2 < 4; ++n2) {
                    const int r = n2 * 16 + lr;
                    short8 bv = *(const short8*)&Vs[b][r * 64 + (((kkc * 4 + lg) ^ (lr & 7)) * 8)];
#pragma unroll
                    for (int m = 0; m < 2; ++m) of[m][n2] = MFMA16(pa[m][kkc], bv, of[m][n2]);
                }
            }
            __builtin_amdgcn_s_setprio(0);
        }

        __syncthreads();
    }

    // final l per q-row, redistributed through the per-wave L buffer
#pragma unroll
    for (int m = 0; m < 2; ++m) {
        float l = lrun[m];
        l += __shfl_xor(l, 16);
        l += __shfl_xor(l, 32);
        Lls[w][m * 16 + lr] = l;  // all lg write the same value
    }
    const int bb = bh >> 4, h = bh & 15;
#pragma unroll
    for (int m = 0; m < 2; ++m)
#pragma unroll
        for (int j = 0; j < 4; ++j) {
            float inv = 1.f / Lls[w][m * 16 + lg * 4 + j];
            int orow = wrow0 + m * 16 + lg * 4 + j;
            size_t ob = ((size_t)(bb * 1024 + orow)) * 1024 + h * 64;
#pragma unroll
            for (int n2 = 0; n2 < 4; ++n2)
                o[ob + n2 * 16 + lr] = f2b(of[m][n2][j] * inv);
        }
}

extern "C" void kernel_launch(void* const* d_in, const int* in_sizes, int n_in, void* d_out,
                              int out_size, void* d_ws, size_t ws_size, hipStream_t stream) {
    const float* x = (const float*)d_in[0];
    const float* scale = (const float*)d_in[1];
    const float* w_qkv = (const float*)d_in[2];
    const float* w_out = (const float*)d_in[3];
    const float* theta = (const float*)d_in[4];
    float* out = (float*)d_out;

    char* p = (char*)d_ws;
    unsigned short* xn = (unsigned short*)p;      p += (size_t)8192 * 1024 * 2;
    unsigned short* wqb = (unsigned short*)p;     p += (size_t)3072 * 1024 * 2;
    unsigned short* wob = (unsigned short*)p;     p += (size_t)1024 * 1024 * 2;
    unsigned short* qb_ = (unsigned short*)p;     p += (size_t)128 * 1024 * 64 * 2;
    unsigned short* kb_ = (unsigned short*)p;     p += (size_t)128 * 1024 * 64 * 2;
    unsigned short* vb_ = (unsigned short*)p;     p += (size_t)128 * 1024 * 64 * 2;  // V^T (B,H,D,S)
    unsigned short* ob_ = (unsigned short*)p;     p += (size_t)8192 * 1024 * 2;

    rmsnorm_kernel<<<8192, 256, 0, stream>>>(x, scale, xn);
    f2b_kernel<<<3072, 256, 0, stream>>>(w_qkv, wqb, 786432);
    f2b_kernel<<<1024, 256, 0, stream>>>(w_out, wob, 262144);
    gemm_bt<0><<<1536, 256, 0, stream>>>(xn, wqb, qb_, kb_, vb_, nullptr, nullptr, theta);
    attn_kernel<<<512, 512, 0, stream>>>(qb_, kb_, vb_, ob_);
    gemm_bt<1><<<512, 256, 0, stream>>>(ob_, wob, nullptr, nullptr, nullptr, x, out, nullptr);
}